// Round 1
// baseline (207.818 us; speedup 1.0000x reference)
//
#include <hip/hip_runtime.h>
#include <hip/hip_bf16.h>

// Centroid update: per-class mean of embed rows, blended with old centroid.
//   sums[c,:]  = sum_{i: y[i]==c} embed[i,:]
//   out[c,:]   = 0.3 * sums[c,:]/count[c] + 0.7 * centroid[c,:]
//
// Strategy: one block per class (1000 blocks, 256 threads). Each thread owns
// 4 consecutive dims (256*4 = 1024 = EMBED_DIM) as float4. The block scans y
// in chunks of 1024 (int4 per thread), compacts matching row indices into an
// LDS list, then all threads gather those embed rows with fully coalesced
// float4 loads. y (128 KB) lives in L2 after first touch, so the per-block
// rescan is L2-served; embed (128 MiB) is read exactly once device-wide.

#define BATCH       32768
#define EMBED_DIM   1024
#define NUM_CLASSES 1000
#define FACTOR      0.3f
#define CHUNK       1024   // y elements scanned per block iteration (4 per thread)

__global__ __launch_bounds__(256) void centroid_kernel(
    const float* __restrict__ embed,
    const int*   __restrict__ y,
    const float* __restrict__ centroid,
    float*       __restrict__ out)
{
    const int c   = blockIdx.x;      // class this block reduces
    const int tid = threadIdx.x;

    __shared__ int rows[CHUNK];      // matched row indices for current chunk
    __shared__ int nmatch;

    float4 acc = make_float4(0.f, 0.f, 0.f, 0.f);
    int count = 0;

    const int ybase_t = tid * 4;     // this thread's offset within a chunk

    for (int base = 0; base < BATCH; base += CHUNK) {
        if (tid == 0) nmatch = 0;
        __syncthreads();

        // Coalesced vector load of 4 labels per thread.
        const int4 yv = *reinterpret_cast<const int4*>(y + base + ybase_t);
        if (yv.x == c) { int p = atomicAdd(&nmatch, 1); rows[p] = base + ybase_t + 0; }
        if (yv.y == c) { int p = atomicAdd(&nmatch, 1); rows[p] = base + ybase_t + 1; }
        if (yv.z == c) { int p = atomicAdd(&nmatch, 1); rows[p] = base + ybase_t + 2; }
        if (yv.w == c) { int p = atomicAdd(&nmatch, 1); rows[p] = base + ybase_t + 3; }
        __syncthreads();

        const int m = nmatch;        // same value block-wide
        for (int j = 0; j < m; ++j) {
            const int r = rows[j];   // LDS broadcast read — no bank conflict
            const float4 v = *reinterpret_cast<const float4*>(
                embed + (size_t)r * EMBED_DIM + ybase_t);
            acc.x += v.x; acc.y += v.y; acc.z += v.z; acc.w += v.w;
        }
        count += m;
        __syncthreads();             // protect rows[] before next chunk reuse
    }

    // Epilogue: mean, blend, store. count==0 -> 0/0 = NaN, matching reference.
    const float inv = 1.0f / (float)count;
    const size_t o = (size_t)c * EMBED_DIM + ybase_t;
    const float4 cen = *reinterpret_cast<const float4*>(centroid + o);
    float4 res;
    res.x = FACTOR * (acc.x * inv) + (1.0f - FACTOR) * cen.x;
    res.y = FACTOR * (acc.y * inv) + (1.0f - FACTOR) * cen.y;
    res.z = FACTOR * (acc.z * inv) + (1.0f - FACTOR) * cen.z;
    res.w = FACTOR * (acc.w * inv) + (1.0f - FACTOR) * cen.w;
    *reinterpret_cast<float4*>(out + o) = res;
}

extern "C" void kernel_launch(void* const* d_in, const int* in_sizes, int n_in,
                              void* d_out, int out_size, void* d_ws, size_t ws_size,
                              hipStream_t stream) {
    const float* embed    = (const float*)d_in[0];  // [32768, 1024]
    const int*   y        = (const int*)d_in[1];    // [32768]
    const float* centroid = (const float*)d_in[2];  // [1000, 1024]
    float*       out      = (float*)d_out;          // [1000, 1024]

    centroid_kernel<<<NUM_CLASSES, 256, 0, stream>>>(embed, y, centroid, out);
}